// Round 2
// baseline (779.619 us; speedup 1.0000x reference)
//
#include <hip/hip_runtime.h>

#define C_IN   128
#define H_IN   56
#define W_IN   56
#define HW     3136      // 56*56
#define CHW    401408    // 128*3136
#define O_OUT  256
#define OHW    802816    // 256*3136

#define BM 256
#define BN 128
#define LDSW 64          // swizzled, unpadded row width (ushorts)
#define LDK 72           // fallback padded layout

typedef __bf16 bf16x8 __attribute__((ext_vector_type(8)));
typedef float  f32x4  __attribute__((ext_vector_type(4)));
typedef unsigned short ushort_t;
typedef ushort_t ushort8 __attribute__((ext_vector_type(8)));

__device__ __forceinline__ ushort_t f2bf(float f) {
    union { float f; unsigned u; } v; v.f = f;
    unsigned r = (v.u + 0x7fffu + ((v.u >> 16) & 1u)) >> 16;
    return (ushort_t)r;
}

// Weights: w[o][c][kh][kw] fp32 -> wbf[pos][o][c] bf16, pos = kh*3+kw
__global__ void wt_kernel(const float* __restrict__ w, ushort_t* __restrict__ wbf) {
    int idx = blockIdx.x * 256 + threadIdx.x;        // 9*256*128 = 294912
    if (idx >= 9 * 256 * 128) return;
    int pos = idx >> 15;
    int rem = idx & 32767;
    int o   = rem >> 7;
    int c   = rem & 127;
    wbf[idx] = f2bf(w[o * 1152 + c * 9 + pos]);
}

// x: fp32 NCHW -> bf16 NHWC (pixel-major, 128 ch contiguous). 16 threads/pixel.
__global__ void xt_kernel(const float* __restrict__ x, ushort_t* __restrict__ xb) {
    int idx = blockIdx.x * 256 + threadIdx.x;        // 100352*16 = 1605632
    int p  = idx >> 4;
    int cg = idx & 15;
    int n  = p / HW;
    int hw = p - n * HW;
    const float* src = x + (long)n * CHW + (long)(cg * 8) * HW + hw;
    ushort8 v;
    #pragma unroll
    for (int j = 0; j < 8; ++j) v[j] = f2bf(src[j * HW]);
    *(ushort8*)(xb + (long)p * 128 + cg * 8) = v;
}

// Fast path: implicit GEMM from bf16 NHWC x. XOR-swizzled LDS (49.2 KB -> 3 blocks/CU).
__global__ __launch_bounds__(512, 6)
void conv2_kernel(const ushort_t* __restrict__ xb, const ushort_t* __restrict__ wbf,
                  const float* __restrict__ bias, float* __restrict__ out) {
    __shared__ ushort_t As[BM * LDSW];   // 32768 B
    __shared__ ushort_t Bs[BN * LDSW];   // 16384 B

    const int tid  = threadIdx.x;
    const int lane = tid & 63;
    const int wave = tid >> 6;
    const int wm   = wave >> 1;
    const int wn   = wave & 1;
    const int l15  = lane & 15;
    const int quad = lane >> 4;

    const int pix_base = blockIdx.x * BN;

    // B-staging: thread owns pixel bpx, ushort8-groups {bg0, bg0+1} of each 64-ch half
    const int bpx = tid >> 2;            // 0..127
    const int bg0 = (tid & 3) * 2;       // 0,2,4,6
    const int p   = pix_base + bpx;
    const int n_img = p / HW;
    const int hw    = p - n_img * HW;
    const int h     = hw / W_IN;
    const int w_    = hw - h * W_IN;

    // A-staging: thread owns o = ao + s*64, group ag
    const int ao = tid >> 3;             // 0..63
    const int ag = tid & 7;

    f32x4 acc[4][4];
    #pragma unroll
    for (int t = 0; t < 4; ++t)
        #pragma unroll
        for (int u = 0; u < 4; ++u)
            acc[t][u] = f32x4{0.f, 0.f, 0.f, 0.f};

    for (int pos = 0; pos < 9; ++pos) {
        const int dh = pos / 3 - 1;
        const int dw = pos - (pos / 3) * 3 - 1;
        const int ih = h + dh;
        const int iw = w_ + dw;
        const bool valid = ((unsigned)ih < (unsigned)H_IN) && ((unsigned)iw < (unsigned)W_IN);
        const ushort_t* bsrc = xb + (long)(p + dh * W_IN + dw) * 128;

        #pragma unroll
        for (int half = 0; half < 2; ++half) {
            const int c0 = half * 64;

            // ---- stage A: wbf[pos][o][c0+ag*8..] -> As swizzled
            {
                const ushort_t* wsrc = wbf + pos * 32768 + c0;
                #pragma unroll
                for (int s = 0; s < 4; ++s) {
                    const int o = ao + s * 64;
                    ushort8 v = *(const ushort8*)(wsrc + (o << 7) + ag * 8);
                    *(ushort8*)(&As[o * LDSW + ((ag ^ (o & 7)) * 8)]) = v;
                }
            }
            // ---- stage B: xb (zero-padded) -> Bs swizzled
            {
                #pragma unroll
                for (int q = 0; q < 2; ++q) {
                    const int g = bg0 + q;
                    ushort8 v;
                    if (valid) v = *(const ushort8*)(bsrc + c0 + g * 8);
                    else       v = ushort8{0,0,0,0,0,0,0,0};
                    *(ushort8*)(&Bs[bpx * LDSW + ((g ^ (bpx & 7)) * 8)]) = v;
                }
            }
            __syncthreads();

            #pragma unroll
            for (int ks = 0; ks < 2; ++ks) {
                bf16x8 af[4], bfv[4];
                const int k16 = ks * 4 + quad;
                #pragma unroll
                for (int t = 0; t < 4; ++t) {
                    const int row = wm * 64 + t * 16 + l15;
                    af[t] = *(const bf16x8*)(&As[row * LDSW + ((k16 ^ (row & 7)) * 8)]);
                }
                #pragma unroll
                for (int u = 0; u < 4; ++u) {
                    const int col = wn * 64 + u * 16 + l15;
                    bfv[u] = *(const bf16x8*)(&Bs[col * LDSW + ((k16 ^ (col & 7)) * 8)]);
                }
                #pragma unroll
                for (int t = 0; t < 4; ++t)
                    #pragma unroll
                    for (int u = 0; u < 4; ++u)
                        acc[t][u] = __builtin_amdgcn_mfma_f32_16x16x32_bf16(af[t], bfv[u], acc[t][u], 0, 0, 0);
            }
            __syncthreads();
        }
    }

    #pragma unroll
    for (int u = 0; u < 4; ++u) {
        const int col = wn * 64 + u * 16 + l15;
        const int pp  = pix_base + col;
        const int nn  = pp / HW;
        const int hw2 = pp - nn * HW;
        const long obase = (long)nn * OHW + hw2;
        #pragma unroll
        for (int t = 0; t < 4; ++t) {
            const int o_base = wm * 64 + t * 16 + quad * 4;
            #pragma unroll
            for (int r = 0; r < 4; ++r) {
                const int o = o_base + r;
                out[obase + (long)o * HW] = acc[t][u][r] + bias[o];
            }
        }
    }
}

// ---- Fallback (round-1, known-correct): used only if ws_size can't hold xb ----
__global__ __launch_bounds__(512, 4)
void conv_kernel(const float* __restrict__ x, const ushort_t* __restrict__ wbf,
                 const float* __restrict__ bias, float* __restrict__ out) {
    __shared__ ushort_t As[BM * LDK];
    __shared__ ushort_t Bs[BN * LDK];

    const int tid  = threadIdx.x;
    const int lane = tid & 63;
    const int wave = tid >> 6;
    const int wm   = wave >> 1;
    const int wn   = wave & 1;
    const int l15  = lane & 15;
    const int quad = lane >> 4;

    const int pix_base = blockIdx.x * BN;
    const int px  = tid & 127;
    const int cg0 = tid >> 7;
    const int p   = pix_base + px;
    const int n_img = p / HW;
    const int hw    = p - n_img * HW;
    const int h     = hw / W_IN;
    const int w_    = hw - h * W_IN;
    const float* ximg = x + (long)n_img * CHW;

    f32x4 acc[4][4];
    #pragma unroll
    for (int t = 0; t < 4; ++t)
        #pragma unroll
        for (int u = 0; u < 4; ++u)
            acc[t][u] = f32x4{0.f, 0.f, 0.f, 0.f};

    for (int pos = 0; pos < 9; ++pos) {
        const int dh = pos / 3 - 1;
        const int dw = pos - (pos / 3) * 3 - 1;
        const int ih = h + dh;
        const int iw = w_ + dw;
        const bool valid = ((unsigned)ih < (unsigned)H_IN) && ((unsigned)iw < (unsigned)W_IN);
        const float* xsrc = ximg + ih * W_IN + iw;

        for (int half = 0; half < 2; ++half) {
            const int c0 = half * 64;
            {
                const ushort_t* wsrc = wbf + ((pos * 256) << 7) + c0;
                #pragma unroll
                for (int s = 0; s < 4; ++s) {
                    const int o  = (tid >> 3) + s * 64;
                    const int cg = tid & 7;
                    ushort8 v = *(const ushort8*)(wsrc + (o << 7) + cg * 8);
                    *(ushort8*)(&As[o * LDK + cg * 8]) = v;
                }
            }
            {
                #pragma unroll
                for (int s = 0; s < 2; ++s) {
                    const int cg = cg0 + s * 4;
                    const float* src = xsrc + (long)(c0 + cg * 8) * HW;
                    ushort8 v;
                    #pragma unroll
                    for (int j = 0; j < 8; ++j) {
                        float f = valid ? src[j * HW] : 0.0f;
                        v[j] = f2bf(f);
                    }
                    *(ushort8*)(&Bs[px * LDK + cg * 8]) = v;
                }
            }
            __syncthreads();

            #pragma unroll
            for (int ks = 0; ks < 2; ++ks) {
                bf16x8 af[4], bfv[4];
                #pragma unroll
                for (int t = 0; t < 4; ++t) {
                    const int row = wm * 64 + t * 16 + l15;
                    af[t] = *(const bf16x8*)(&As[row * LDK + ks * 32 + quad * 8]);
                }
                #pragma unroll
                for (int u = 0; u < 4; ++u) {
                    const int col = wn * 64 + u * 16 + l15;
                    bfv[u] = *(const bf16x8*)(&Bs[col * LDK + ks * 32 + quad * 8]);
                }
                #pragma unroll
                for (int t = 0; t < 4; ++t)
                    #pragma unroll
                    for (int u = 0; u < 4; ++u)
                        acc[t][u] = __builtin_amdgcn_mfma_f32_16x16x32_bf16(af[t], bfv[u], acc[t][u], 0, 0, 0);
            }
            __syncthreads();
        }
    }

    #pragma unroll
    for (int u = 0; u < 4; ++u) {
        const int col = wn * 64 + u * 16 + l15;
        const int pp  = pix_base + col;
        const int nn  = pp / HW;
        const int hw2 = pp - nn * HW;
        const long obase = (long)nn * OHW + hw2;
        #pragma unroll
        for (int t = 0; t < 4; ++t) {
            const int o_base = wm * 64 + t * 16 + quad * 4;
            #pragma unroll
            for (int r = 0; r < 4; ++r) {
                const int o = o_base + r;
                out[obase + (long)o * HW] = acc[t][u][r] + bias[o];
            }
        }
    }
}

extern "C" void kernel_launch(void* const* d_in, const int* in_sizes, int n_in,
                              void* d_out, int out_size, void* d_ws, size_t ws_size,
                              hipStream_t stream) {
    const float* x    = (const float*)d_in[0];
    const float* w    = (const float*)d_in[1];
    const float* bias = (const float*)d_in[2];
    float* out        = (float*)d_out;

    ushort_t* wbf = (ushort_t*)d_ws;                       // 589,824 B
    ushort_t* xb  = (ushort_t*)((char*)d_ws + 589824);     // 25,690,112 B

    const size_t need = 589824u + 25690112u;

    hipLaunchKernelGGL(wt_kernel, dim3(1152), dim3(256), 0, stream, w, wbf);
    if (ws_size >= need) {
        hipLaunchKernelGGL(xt_kernel, dim3(6272), dim3(256), 0, stream, x, xb);
        hipLaunchKernelGGL(conv2_kernel, dim3(100352 / BN), dim3(512), 0, stream,
                           xb, wbf, bias, out);
    } else {
        hipLaunchKernelGGL(conv_kernel, dim3(100352 / BN), dim3(512), 0, stream,
                           x, wbf, bias, out);
    }
}

// Round 3
// 226.200 us; speedup vs baseline: 3.4466x; 3.4466x over previous
//
#include <hip/hip_runtime.h>

#define C_IN   128
#define H_IN   56
#define W_IN   56
#define HW     3136      // 56*56
#define CHW    401408    // 128*3136
#define O_OUT  256
#define OHW    802816    // 256*3136

#define BM 256
#define BN 128
#define LDSW 64          // swizzled, unpadded row width (ushorts)
#define LDK 72           // fallback padded layout
#define XTP 132          // xt transpose LDS row stride (ushorts), 16B-aligned

typedef __bf16 bf16x8 __attribute__((ext_vector_type(8)));
typedef float  f32x4  __attribute__((ext_vector_type(4)));
typedef unsigned short ushort_t;
typedef ushort_t ushort8 __attribute__((ext_vector_type(8)));

__device__ __forceinline__ ushort_t f2bf(float f) {
    union { float f; unsigned u; } v; v.f = f;
    unsigned r = (v.u + 0x7fffu + ((v.u >> 16) & 1u)) >> 16;
    return (ushort_t)r;
}

// Weights: w[o][c][kh][kw] fp32 -> wbf[pos][o][c] bf16, pos = kh*3+kw
__global__ void wt_kernel(const float* __restrict__ w, ushort_t* __restrict__ wbf) {
    int idx = blockIdx.x * 256 + threadIdx.x;        // 9*256*128 = 294912
    if (idx >= 9 * 256 * 128) return;
    int pos = idx >> 15;
    int rem = idx & 32767;
    int o   = rem >> 7;
    int c   = rem & 127;
    wbf[idx] = f2bf(w[o * 1152 + c * 9 + pos]);
}

// x: fp32 NCHW -> bf16 NHWC via LDS transpose. Block = 256 thr, tile = 64 pixels x 128 ch.
// HW = 49*64 so a tile never crosses an image boundary.
__global__ __launch_bounds__(256)
void xt_kernel(const float* __restrict__ x, ushort_t* __restrict__ xb) {
    __shared__ ushort_t T[64 * XTP];     // 16896 B
    const int t  = threadIdx.x;
    const int tb = blockIdx.x;           // 0..1567
    const int n   = tb / 49;
    const int hw0 = (tb - n * 49) * 64;
    const float* src = x + (long)n * CHW + hw0;

    // Phase 1: coalesced float4 reads along hw, scalar bf16 writes into transposed LDS
    #pragma unroll
    for (int i = 0; i < 8; ++i) {
        const int g  = i * 256 + t;      // 0..2047 float4-units, channel-major
        const int c  = g >> 4;           // 0..127
        const int p4 = g & 15;           // float4 index within the 64-pixel row
        f32x4 v = *(const f32x4*)(src + (long)c * HW + p4 * 4);
        #pragma unroll
        for (int j = 0; j < 4; ++j)
            T[(p4 * 4 + j) * XTP + c] = f2bf(v[j]);
    }
    __syncthreads();

    // Phase 2: contiguous ushort8 reads per pixel, fully-coalesced global writes
    ushort_t* dst = xb + ((long)n * HW + hw0) * 128;
    #pragma unroll
    for (int s = 0; s < 4; ++s) {
        const int idx = s * 256 + t;     // 0..1023 ushort8-units, pixel-major
        const int pix = idx >> 4;
        const int grp = idx & 15;
        ushort8 v = *(const ushort8*)(&T[pix * XTP + grp * 8]);
        *(ushort8*)(dst + pix * 128 + grp * 8) = v;
    }
}

// Fast path: implicit GEMM from bf16 NHWC x. XOR-swizzled LDS, zero bank conflicts.
__global__ __launch_bounds__(512, 4)
void conv2_kernel(const ushort_t* __restrict__ xb, const ushort_t* __restrict__ wbf,
                  const float* __restrict__ bias, float* __restrict__ out) {
    __shared__ ushort_t As[BM * LDSW];   // 32768 B
    __shared__ ushort_t Bs[BN * LDSW];   // 16384 B

    const int tid  = threadIdx.x;
    const int lane = tid & 63;
    const int wave = tid >> 6;
    const int wm   = wave >> 1;
    const int wn   = wave & 1;
    const int l15  = lane & 15;
    const int quad = lane >> 4;

    const int pix_base = blockIdx.x * BN;

    const int bpx = tid >> 2;            // 0..127
    const int bg0 = (tid & 3) * 2;       // 0,2,4,6
    const int p   = pix_base + bpx;
    const int n_img = p / HW;
    const int hw    = p - n_img * HW;
    const int h     = hw / W_IN;
    const int w_    = hw - h * W_IN;

    const int ao = tid >> 3;             // 0..63
    const int ag = tid & 7;

    f32x4 acc[4][4];
    #pragma unroll
    for (int t = 0; t < 4; ++t)
        #pragma unroll
        for (int u = 0; u < 4; ++u)
            acc[t][u] = f32x4{0.f, 0.f, 0.f, 0.f};

    for (int pos = 0; pos < 9; ++pos) {
        const int dh = pos / 3 - 1;
        const int dw = pos - (pos / 3) * 3 - 1;
        const int ih = h + dh;
        const int iw = w_ + dw;
        const bool valid = ((unsigned)ih < (unsigned)H_IN) && ((unsigned)iw < (unsigned)W_IN);
        const ushort_t* bsrc = xb + (long)(p + dh * W_IN + dw) * 128;

        #pragma unroll
        for (int half = 0; half < 2; ++half) {
            const int c0 = half * 64;

            {
                const ushort_t* wsrc = wbf + pos * 32768 + c0;
                #pragma unroll
                for (int s = 0; s < 4; ++s) {
                    const int o = ao + s * 64;
                    ushort8 v = *(const ushort8*)(wsrc + (o << 7) + ag * 8);
                    *(ushort8*)(&As[o * LDSW + ((ag ^ (o & 7)) * 8)]) = v;
                }
            }
            {
                #pragma unroll
                for (int q = 0; q < 2; ++q) {
                    const int g = bg0 + q;
                    ushort8 v;
                    if (valid) v = *(const ushort8*)(bsrc + c0 + g * 8);
                    else       v = ushort8{0,0,0,0,0,0,0,0};
                    *(ushort8*)(&Bs[bpx * LDSW + ((g ^ (bpx & 7)) * 8)]) = v;
                }
            }
            __syncthreads();

            #pragma unroll
            for (int ks = 0; ks < 2; ++ks) {
                bf16x8 af[4], bfv[4];
                const int k16 = ks * 4 + quad;
                #pragma unroll
                for (int t = 0; t < 4; ++t) {
                    const int row = wm * 64 + t * 16 + l15;
                    af[t] = *(const bf16x8*)(&As[row * LDSW + ((k16 ^ (row & 7)) * 8)]);
                }
                #pragma unroll
                for (int u = 0; u < 4; ++u) {
                    const int col = wn * 64 + u * 16 + l15;
                    bfv[u] = *(const bf16x8*)(&Bs[col * LDSW + ((k16 ^ (col & 7)) * 8)]);
                }
                #pragma unroll
                for (int t = 0; t < 4; ++t)
                    #pragma unroll
                    for (int u = 0; u < 4; ++u)
                        acc[t][u] = __builtin_amdgcn_mfma_f32_16x16x32_bf16(af[t], bfv[u], acc[t][u], 0, 0, 0);
            }
            __syncthreads();
        }
    }

    #pragma unroll
    for (int u = 0; u < 4; ++u) {
        const int col = wn * 64 + u * 16 + l15;
        const int pp  = pix_base + col;
        const int nn  = pp / HW;
        const int hw2 = pp - nn * HW;
        const long obase = (long)nn * OHW + hw2;
        #pragma unroll
        for (int t = 0; t < 4; ++t) {
            const int o_base = wm * 64 + t * 16 + quad * 4;
            #pragma unroll
            for (int r = 0; r < 4; ++r) {
                const int o = o_base + r;
                out[obase + (long)o * HW] = acc[t][u][r] + bias[o];
            }
        }
    }
}

// ---- Fallback (round-1, known-correct): used only if ws_size can't hold xb ----
__global__ __launch_bounds__(512, 4)
void conv_kernel(const float* __restrict__ x, const ushort_t* __restrict__ wbf,
                 const float* __restrict__ bias, float* __restrict__ out) {
    __shared__ ushort_t As[BM * LDK];
    __shared__ ushort_t Bs[BN * LDK];

    const int tid  = threadIdx.x;
    const int lane = tid & 63;
    const int wave = tid >> 6;
    const int wm   = wave >> 1;
    const int wn   = wave & 1;
    const int l15  = lane & 15;
    const int quad = lane >> 4;

    const int pix_base = blockIdx.x * BN;
    const int px  = tid & 127;
    const int cg0 = tid >> 7;
    const int p   = pix_base + px;
    const int n_img = p / HW;
    const int hw    = p - n_img * HW;
    const int h     = hw / W_IN;
    const int w_    = hw - h * W_IN;
    const float* ximg = x + (long)n_img * CHW;

    f32x4 acc[4][4];
    #pragma unroll
    for (int t = 0; t < 4; ++t)
        #pragma unroll
        for (int u = 0; u < 4; ++u)
            acc[t][u] = f32x4{0.f, 0.f, 0.f, 0.f};

    for (int pos = 0; pos < 9; ++pos) {
        const int dh = pos / 3 - 1;
        const int dw = pos - (pos / 3) * 3 - 1;
        const int ih = h + dh;
        const int iw = w_ + dw;
        const bool valid = ((unsigned)ih < (unsigned)H_IN) && ((unsigned)iw < (unsigned)W_IN);
        const float* xsrc = ximg + ih * W_IN + iw;

        for (int half = 0; half < 2; ++half) {
            const int c0 = half * 64;
            {
                const ushort_t* wsrc = wbf + ((pos * 256) << 7) + c0;
                #pragma unroll
                for (int s = 0; s < 4; ++s) {
                    const int o  = (tid >> 3) + s * 64;
                    const int cg = tid & 7;
                    ushort8 v = *(const ushort8*)(wsrc + (o << 7) + cg * 8);
                    *(ushort8*)(&As[o * LDK + cg * 8]) = v;
                }
            }
            {
                #pragma unroll
                for (int s = 0; s < 2; ++s) {
                    const int cg = cg0 + s * 4;
                    const float* src = xsrc + (long)(c0 + cg * 8) * HW;
                    ushort8 v;
                    #pragma unroll
                    for (int j = 0; j < 8; ++j) {
                        float f = valid ? src[j * HW] : 0.0f;
                        v[j] = f2bf(f);
                    }
                    *(ushort8*)(&Bs[px * LDK + cg * 8]) = v;
                }
            }
            __syncthreads();

            #pragma unroll
            for (int ks = 0; ks < 2; ++ks) {
                bf16x8 af[4], bfv[4];
                #pragma unroll
                for (int t = 0; t < 4; ++t) {
                    const int row = wm * 64 + t * 16 + l15;
                    af[t] = *(const bf16x8*)(&As[row * LDK + ks * 32 + quad * 8]);
                }
                #pragma unroll
                for (int u = 0; u < 4; ++u) {
                    const int col = wn * 64 + u * 16 + l15;
                    bfv[u] = *(const bf16x8*)(&Bs[col * LDK + ks * 32 + quad * 8]);
                }
                #pragma unroll
                for (int t = 0; t < 4; ++t)
                    #pragma unroll
                    for (int u = 0; u < 4; ++u)
                        acc[t][u] = __builtin_amdgcn_mfma_f32_16x16x32_bf16(af[t], bfv[u], acc[t][u], 0, 0, 0);
            }
            __syncthreads();
        }
    }

    #pragma unroll
    for (int u = 0; u < 4; ++u) {
        const int col = wn * 64 + u * 16 + l15;
        const int pp  = pix_base + col;
        const int hw2 = pp - (pp / HW) * HW;
        const long obase = (long)(pp / HW) * OHW + hw2;
        #pragma unroll
        for (int t = 0; t < 4; ++t) {
            const int o_base = wm * 64 + t * 16 + quad * 4;
            #pragma unroll
            for (int r = 0; r < 4; ++r) {
                const int o = o_base + r;
                out[obase + (long)o * HW] = acc[t][u][r] + bias[o];
            }
        }
    }
}

extern "C" void kernel_launch(void* const* d_in, const int* in_sizes, int n_in,
                              void* d_out, int out_size, void* d_ws, size_t ws_size,
                              hipStream_t stream) {
    const float* x    = (const float*)d_in[0];
    const float* w    = (const float*)d_in[1];
    const float* bias = (const float*)d_in[2];
    float* out        = (float*)d_out;

    ushort_t* wbf = (ushort_t*)d_ws;                       // 589,824 B
    ushort_t* xb  = (ushort_t*)((char*)d_ws + 589824);     // 25,690,112 B

    const size_t need = 589824u + 25690112u;

    hipLaunchKernelGGL(wt_kernel, dim3(1152), dim3(256), 0, stream, w, wbf);
    if (ws_size >= need) {
        hipLaunchKernelGGL(xt_kernel, dim3(1568), dim3(256), 0, stream, x, xb);
        hipLaunchKernelGGL(conv2_kernel, dim3(100352 / BN), dim3(512), 0, stream,
                           xb, wbf, bias, out);
    } else {
        hipLaunchKernelGGL(conv_kernel, dim3(100352 / BN), dim3(512), 0, stream,
                           x, wbf, bias, out);
    }
}